// Round 10
// baseline (335.646 us; speedup 1.0000x reference)
//
#include <hip/hip_runtime.h>

#define T_STEPS 365
#define BATCH   2048
#define INP     9
#define HID     50
#define MB      16          // batch per block (MFMA col dim)
#define NBLK    (BATCH/MB)  // 128
#define NT      512         // 8 waves: 0-6 compute (2 tiles each), 7 util
#define NWC     7
#define NTILES  13          // 208 gate rows >= 200
#define L2E     1.4426950408889634f

typedef __attribute__((ext_vector_type(8))) short short8;
typedef __attribute__((ext_vector_type(4))) float float4v;

__device__ __forceinline__ unsigned f2bf(float v) {
    unsigned u = __builtin_bit_cast(unsigned, v);
    return (u + 0x7FFFu + ((u >> 16) & 1u)) >> 16;
}

// lgkm-only phase barrier: LDS drains, global loads/stores stay in flight.
#define PHASE_BARRIER() do {                                  \
    asm volatile("s_waitcnt lgkmcnt(0)" ::: "memory");        \
    __builtin_amdgcn_s_barrier();                             \
    __builtin_amdgcn_sched_barrier(0);                        \
} while (0)

// Transposed LDS: HX[p][(k>>3)*128 + m*8 + (k&7)] (ushort units).
// K layout: 0-49 h0 | 50-58 x | 59-63 zero | 64-113 h1 | 114-127 zero.
// A wave's b128 fragment read (lane = (mcol,kgrp)) is a CONTIGUOUS 1 KB
// block -> zero bank conflicts, no swizzle arithmetic.
__device__ __forceinline__ int tx_off(int m, int k) {
    return ((k >> 3) * 128) + m * 8 + (k & 7);
}

// rcp-merged LSTM cell: 5 exp2 + 3 rcp (rcp(a)*rcp(b) = rcp(a*b)).
// Inputs are exp2-prescaled gate pre-activations (-L2E for i,f,o; -2L2E for g).
__device__ __forceinline__ float cell_(float a0, float a1, float a2, float a3,
                                       float& c) {
    const float Ei = __builtin_amdgcn_exp2f(a0);
    const float Ef = __builtin_amdgcn_exp2f(a1);
    const float Eg = __builtin_amdgcn_exp2f(a2);
    const float Eo = __builtin_amdgcn_exp2f(a3);
    const float ig = (1.f - Eg) * __builtin_amdgcn_rcpf((1.f + Ei) * (1.f + Eg));
    c = __builtin_amdgcn_rcpf(1.f + Ef) * c + ig;
    const float Ec = __builtin_amdgcn_exp2f(c * (-2.f * L2E));
    return (1.f - Ec) * __builtin_amdgcn_rcpf((1.f + Eo) * (1.f + Ec));
}

// Merged-role LSTM, 8 waves: wave w owns tiles {w, w+7} and computes BOTH
// layer0 (step ph) and layer1 (step ph-1) chains per tile. f0-f3 fragment
// reads are shared across all 4 chains. FC head rides as spare gate row 200
// (weights = fc_w over the h1 K-section, bias = fc_b) -> chain B's MFMA
// emits the FC output directly; lanes (tile12, kgrp2, reg0) store it.
__global__ __launch_bounds__(NT, 2)
void lstm_fuse8(const float* __restrict__ x,
                const float* __restrict__ w_ih0, const float* __restrict__ w_hh0,
                const float* __restrict__ b_ih0, const float* __restrict__ b_hh0,
                const float* __restrict__ w_ih1, const float* __restrict__ w_hh1,
                const float* __restrict__ b_ih1, const float* __restrict__ b_hh1,
                const float* __restrict__ fc_w, const float* __restrict__ fc_b,
                float* __restrict__ out)
{
    __shared__ __align__(16) unsigned short HX[2][2048];   // 8 KB total

    const int tid  = threadIdx.x;
    const int w    = tid >> 6;
    const int lid  = tid & 63;
    const int mcol = lid & 15;
    const int kgrp = lid >> 4;
    const int kb8  = kgrp * 8;
    const int b0   = blockIdx.x * MB;
    const bool cw  = (w < NWC);

    // ---- per-tile weights (gate-interleaved rows: r = 4*unit + gate ->
    //      original row = gate*50 + unit) ----
    short8 wk0[2][2], wk1[2][2], wk2[2][2];
    float  bs0[2][4], bs1[2][4];
    float  cst0[2] = {0.f, 0.f}, cst1[2] = {0.f, 0.f};

    #pragma unroll
    for (int tt = 0; tt < 2; ++tt) {
        const int T  = w + NWC * tt;             // wave w: tiles w, w+7
        const bool tv = cw && (T < NTILES);
        const int r  = T * 16 + mcol;
        const bool rv = tv && (r < 4 * HID);
        const int u_r = r >> 2, g_r = r & 3;
        const int orig = g_r * HID + u_r;
        const float rsc = (g_r == 2) ? (-2.f * L2E) : (-L2E);
        const bool fcrow = tv && (T == 12) && (mcol == 8);   // spare row 200
        #pragma unroll
        for (int q = 0; q < 2; ++q) {
            short8 a{}, b{}, c{};
            #pragma unroll
            for (int j = 0; j < 8; ++j) {
                const int k = q * 32 + kb8 + j;
                float v0 = 0.f, v1 = 0.f, v2 = 0.f;
                if (rv) {
                    if (k < HID) {
                        v0 = w_hh0[orig * HID + k] * rsc;
                        v1 = w_ih1[orig * HID + k] * rsc;
                        v2 = w_hh1[orig * HID + k] * rsc;
                    } else if (k < HID + INP) {
                        v0 = w_ih0[orig * INP + (k - HID)] * rsc;
                    }
                }
                if (fcrow) v2 = (k < HID) ? fc_w[k] : 0.f;   // unscaled FC row
                a[j] = (short)f2bf(v0);
                b[j] = (short)f2bf(v1);
                c[j] = (short)f2bf(v2);
            }
            wk0[tt][q] = a; wk1[tt][q] = b; wk2[tt][q] = c;
        }
        #pragma unroll
        for (int rr = 0; rr < 4; ++rr) {
            const int row = T * 16 + kgrp * 4 + rr;   // = 4*u + gate(rr)
            const bool bv = tv && (row < 4 * HID);
            const int uu = row >> 2;
            const float bsc = (rr == 2) ? (-2.f * L2E) : (-L2E);
            bs0[tt][rr] = bv ? (b_ih0[rr * HID + uu] + b_hh0[rr * HID + uu]) * bsc : 0.f;
            bs1[tt][rr] = bv ? (b_ih1[rr * HID + uu] + b_hh1[rr * HID + uu]) * bsc : 0.f;
            if (tv && row == 4 * HID) bs1[tt][rr] = fc_b[0];  // FC bias (row 200)
        }
    }

    // ---- util wave (w == 7): lanes 0-47 stage x (3 values each) ----
    const bool xact = (!cw) && (lid < 48);
    float xr[3] = {0.f, 0.f, 0.f};

    // ---- LDS init ----
    for (int i = tid; i < 2 * 2048; i += NT) (&HX[0][0])[i] = 0;
    __syncthreads();
    if (xact) {
        #pragma unroll
        for (int q = 0; q < 3; ++q) {
            const int xi = lid * 3 + q;
            if (xi < MB * INP) {
                const int m = xi / INP, j = xi - m * INP;
                // x(0) into buf1 (phase 0 reads cur = 1); xr <- x(1)
                HX[1][tx_off(m, HID + j)] =
                    (unsigned short)f2bf(x[(size_t)(b0 + m) * INP + j]);
                xr[q] = x[((size_t)BATCH + b0 + m) * INP + j];
            }
        }
    }
    __syncthreads();

    for (int ph = 0; ph <= T_STEPS + 1; ++ph) {
        const int cur = (ph + 1) & 1, nxt = ph & 1;

        if (cw) {
            // shared fragments: contiguous-1KB b128 reads, conflict-free.
            const int base = mcol * 8;
            const short8 f0 = *(const short8*)&HX[cur][(kgrp)      * 128 + base];
            const short8 f1 = *(const short8*)&HX[cur][(4  + kgrp) * 128 + base];
            const short8 f2 = *(const short8*)&HX[cur][(8  + kgrp) * 128 + base];
            const short8 f3 = *(const short8*)&HX[cur][(12 + kgrp) * 128 + base];

            #pragma unroll
            for (int tt = 0; tt < 2; ++tt) {
                const int T = w + NWC * tt;
                if (T >= NTILES) continue;
                const int u = T * 4 + kgrp;

                // ---- chain A: layer0 step ph ----
                if (ph < T_STEPS) {
                    float4v acc = {bs0[tt][0], bs0[tt][1], bs0[tt][2], bs0[tt][3]};
                    acc = __builtin_amdgcn_mfma_f32_16x16x32_bf16(wk0[tt][0], f0, acc, 0, 0, 0);
                    acc = __builtin_amdgcn_mfma_f32_16x16x32_bf16(wk0[tt][1], f1, acc, 0, 0, 0);
                    const float h0v = cell_(acc[0], acc[1], acc[2], acc[3], cst0[tt]);
                    if (u < HID) HX[nxt][tx_off(mcol, u)] = (unsigned short)f2bf(h0v);
                }

                // ---- chain B: layer1 step ph-1 (+ FC row) ----
                if (ph >= 1) {
                    float4v accA = {bs1[tt][0], bs1[tt][1], bs1[tt][2], bs1[tt][3]};
                    float4v accB = {0.f, 0.f, 0.f, 0.f};
                    accA = __builtin_amdgcn_mfma_f32_16x16x32_bf16(wk1[tt][0], f0, accA, 0, 0, 0);
                    accB = __builtin_amdgcn_mfma_f32_16x16x32_bf16(wk2[tt][0], f2, accB, 0, 0, 0);
                    accA = __builtin_amdgcn_mfma_f32_16x16x32_bf16(wk1[tt][1], f1, accA, 0, 0, 0);
                    accB = __builtin_amdgcn_mfma_f32_16x16x32_bf16(wk2[tt][1], f3, accB, 0, 0, 0);
                    const float a0 = accA[0] + accB[0];
                    const float a1 = accA[1] + accB[1];
                    const float a2 = accA[2] + accB[2];
                    const float a3 = accA[3] + accB[3];
                    // FC output = row 200 = (tile 12, kgrp 2, reg 0): fc_b + fc_w.h1(ph-2)
                    if (T == 12 && kgrp == 2 && ph >= 2)
                        out[(size_t)(ph - 2) * BATCH + b0 + mcol] = a0;
                    if (ph <= T_STEPS) {
                        const float h1v = cell_(a0, a1, a2, a3, cst1[tt]);
                        if (u < HID) HX[nxt][tx_off(mcol, 64 + u)] = (unsigned short)f2bf(h1v);
                    }
                }
            }
        } else if (xact) {
            // ---- x staging: write x(ph+1) (loaded 2 phases ago), load x(ph+2) ----
            #pragma unroll
            for (int q = 0; q < 3; ++q) {
                const int xi = lid * 3 + q;
                if (xi < MB * INP) {
                    const int m = xi / INP, j = xi - m * INP;
                    float xn = 0.f;
                    if (ph + 2 < T_STEPS)
                        xn = x[((size_t)(ph + 2) * BATCH + b0 + m) * INP + j];
                    if (ph + 1 < T_STEPS)
                        HX[nxt][tx_off(m, HID + j)] = (unsigned short)f2bf(xr[q]);
                    xr[q] = xn;
                }
            }
        }
        PHASE_BARRIER();
    }
}

extern "C" void kernel_launch(void* const* d_in, const int* in_sizes, int n_in,
                              void* d_out, int out_size, void* d_ws, size_t ws_size,
                              hipStream_t stream) {
    const float* x     = (const float*)d_in[0];
    const float* w_ih0 = (const float*)d_in[1];
    const float* w_hh0 = (const float*)d_in[2];
    const float* b_ih0 = (const float*)d_in[3];
    const float* b_hh0 = (const float*)d_in[4];
    const float* w_ih1 = (const float*)d_in[5];
    const float* w_hh1 = (const float*)d_in[6];
    const float* b_ih1 = (const float*)d_in[7];
    const float* b_hh1 = (const float*)d_in[8];
    const float* fc_w  = (const float*)d_in[9];
    const float* fc_b  = (const float*)d_in[10];
    float* out = (float*)d_out;

    lstm_fuse8<<<dim3(NBLK), dim3(NT), 0, stream>>>(
        x, w_ih0, w_hh0, b_ih0, b_hh0,
        w_ih1, w_hh1, b_ih1, b_hh1, fc_w, fc_b, out);
}